// Round 8
// baseline (106.499 us; speedup 1.0000x reference)
//
#include <hip/hip_runtime.h>

#define NBINS 15

typedef float f32x4 __attribute__((ext_vector_type(4)));

__device__ __forceinline__ float rdlane_f(float v, int lane) {
    return __int_as_float(__builtin_amdgcn_readlane(__float_as_int(v), lane));
}
__device__ __forceinline__ float rdfirst_f(float v) {
    return __int_as_float(__builtin_amdgcn_readfirstlane(__float_as_int(v)));
}

// e += value moved by DPP
template <int CTRL, int RMASK>
__device__ __forceinline__ float dpp_add(float e) {
    int moved = __builtin_amdgcn_update_dpp(0, __float_as_int(e), CTRL, RMASK, 0xf, true);
    return e + __int_as_float(moved);
}

// Sum within each 32-lane half entirely on the VALU (no DS-pipe ops):
// leaves sum(lanes 0..31) in lane 31, sum(lanes 32..63) in lane 63.
__device__ __forceinline__ float half32_sum(float e) {
    e = dpp_add<0x111, 0xf>(e);  // row_shr:1
    e = dpp_add<0x112, 0xf>(e);  // row_shr:2
    e = dpp_add<0x114, 0xf>(e);  // row_shr:4
    e = dpp_add<0x118, 0xf>(e);  // row_shr:8   -> lanes 15/31/47/63 hold row-of-16 sums
    e = dpp_add<0x142, 0xa>(e);  // row_bcast:15 into rows 1,3 -> lanes 31,63
    return e;
}

// Two-kernel structure (round-6 fused atomics caused L2 wb/inv thrash, 2.6x
// regression — keep the cheap second launch).
// One wave owns 128 consecutive rows (C=128 fp32).
// R8 single-variable A/B: plain loads instead of nontemporal (nt may defeat
// L2 read-combining on a pure streaming read; no reuse exists either way).
__global__ __launch_bounds__(256) void adafocal_partial(
    const float* __restrict__ inp,
    const int* __restrict__ target,
    const float* __restrict__ bin_uppers,
    const float* __restrict__ gammas,
    float* __restrict__ partial,
    int N)
{
    __shared__ float  s_g[NBINS];
    __shared__ float2 s_coll[4][128];
    __shared__ float  s_wsum[4];

    if (threadIdx.x < NBINS) s_g[threadIdx.x] = gammas[threadIdx.x];
    __syncthreads();

    // interior bin boundaries, forced to SGPRs (wave-uniform, saves 14 VGPRs)
    float u[NBINS - 1];
    #pragma unroll
    for (int i = 0; i < NBINS - 1; ++i) u[i] = rdfirst_f(bin_uppers[i]);

    const int lane  = threadIdx.x & 63;
    const int wid   = threadIdx.x >> 6;
    const int gwave = blockIdx.x * 4 + wid;
    const int wrow0 = gwave * 128;            // first row of this wave's batch

    // 128 targets for the batch: lane l holds rows 2l, 2l+1
    int2 tt = make_int2(0, 0);
    if (wrow0 + 2 * lane + 1 < N)      tt = ((const int2*)target)[(wrow0 >> 1) + lane];
    else if (wrow0 + 2 * lane < N)     tt.x = target[wrow0 + 2 * lane];

    if (wrow0 + 128 <= N) {
        // hot path: no bounds checks; unroll 8 -> 8KB outstanding loads/wave
        #pragma unroll 8
        for (int k = 0; k < 64; ++k) {
            const f32x4 v = *((const f32x4*)(inp + (size_t)(wrow0 + 2 * k) * 128) + lane);

            float e = __expf(v.x) + __expf(v.y) + __expf(v.z) + __expf(v.w);
            e = half32_sum(e);                 // lane31 = row sum, lane63 = row+1 sum

            const int t0 = __builtin_amdgcn_readlane(tt.x, k);
            const int t1 = __builtin_amdgcn_readlane(tt.y, k);
            // x[target]: column c -> lane c>>2 (+32 for upper row), elem c&3
            const float a0  = (t0 & 1) ? v.y : v.x;
            const float b0  = (t0 & 1) ? v.w : v.z;
            const float xt0 = rdlane_f((t0 & 2) ? b0 : a0, t0 >> 2);
            const float a1  = (t1 & 1) ? v.y : v.x;
            const float b1  = (t1 & 1) ? v.w : v.z;
            const float xt1 = rdlane_f((t1 & 2) ? b1 : a1, 32 + (t1 >> 2));

            float2 val;
            val.x = e;
            val.y = (lane < 32) ? xt0 : xt1;
            if ((lane & 31) == 31)
                s_coll[wid][2 * k + (lane >> 5)] = val;
        }
    } else {
        // tail wave (generic N): sentinel (s=1, xt=0) -> exactly 0 contribution
        s_coll[wid][lane]      = make_float2(1.0f, 0.0f);
        s_coll[wid][64 + lane] = make_float2(1.0f, 0.0f);
        for (int k = 0; k < 64; ++k) {
            const int grow = wrow0 + 2 * k;
            if (grow >= N) break;               // uniform
            const bool full = (grow + 1 < N);   // uniform
            f32x4 v = {0.f, 0.f, 0.f, 0.f};
            if (full || lane < 32)
                v = *((const f32x4*)(inp + (size_t)grow * 128) + lane);
            float e = __expf(v.x) + __expf(v.y) + __expf(v.z) + __expf(v.w);
            e = half32_sum(e);
            const int t0 = __builtin_amdgcn_readlane(tt.x, k);
            const int t1 = __builtin_amdgcn_readlane(tt.y, k);
            const float a0  = (t0 & 1) ? v.y : v.x;
            const float b0  = (t0 & 1) ? v.w : v.z;
            const float xt0 = rdlane_f((t0 & 2) ? b0 : a0, t0 >> 2);
            const float a1  = (t1 & 1) ? v.y : v.x;
            const float b1  = (t1 & 1) ? v.w : v.z;
            const float xt1 = rdlane_f((t1 & 2) ? b1 : a1, 32 + (t1 >> 2));
            float2 val;
            val.x = e;
            val.y = (lane < 32) ? xt0 : xt1;
            if (lane == 31 || (full && lane == 63))
                s_coll[wid][2 * k + (lane >> 5)] = val;
        }
    }

    // Phase 2: each lane computes loss for 2 stashed rows (same-wave LDS order)
    float acc = 0.0f;
    #pragma unroll
    for (int h = 0; h < 2; ++h) {
        const float2 cv   = s_coll[wid][64 * h + lane];
        const float logpt = cv.y - __logf(cv.x);
        const float pt    = __expf(logpt);

        // searchsorted(bin_uppers, pt, side='right') = #{uppers <= pt}
        int b = 0;
        #pragma unroll
        for (int i = 0; i < NBINS - 1; ++i)
            b += (u[i] <= pt) ? 1 : 0;

        const float g     = s_g[b];
        const float gsign = (g > 0.0f) ? 1.0f : (g < 0.0f ? -1.0f : 0.0f);
        const float gmag  = fabsf(g);
        const float base  = 1.0f - gsign * pt + 1e-20f;
        const float powv  = (gmag == 1.0f) ? base : __powf(base, gmag);
        acc -= powv * logpt;
    }

    // wave reduce (once per 128 rows)
    #pragma unroll
    for (int m = 1; m < 64; m <<= 1)
        acc += __shfl_xor(acc, m);
    if (lane == 0) s_wsum[wid] = acc;
    __syncthreads();
    if (threadIdx.x == 0)
        partial[blockIdx.x] = (s_wsum[0] + s_wsum[1]) + (s_wsum[2] + s_wsum[3]);
}

__global__ __launch_bounds__(256) void adafocal_final(
    const float* __restrict__ partial, float* __restrict__ out, int nblocks)
{
    __shared__ float s_wsum[4];
    float acc = 0.0f;
    for (int i = threadIdx.x; i < nblocks; i += 256) acc += partial[i];
    #pragma unroll
    for (int m = 1; m < 64; m <<= 1)
        acc += __shfl_xor(acc, m);
    const int lane = threadIdx.x & 63;
    const int wid  = threadIdx.x >> 6;
    if (lane == 0) s_wsum[wid] = acc;
    __syncthreads();
    if (threadIdx.x == 0)
        out[0] = (s_wsum[0] + s_wsum[1]) + (s_wsum[2] + s_wsum[3]);
}

extern "C" void kernel_launch(void* const* d_in, const int* in_sizes, int n_in,
                              void* d_out, int out_size, void* d_ws, size_t ws_size,
                              hipStream_t stream) {
    const float* inp        = (const float*)d_in[0];
    const int*   targetp    = (const int*)d_in[1];
    const float* bin_uppers = (const float*)d_in[2];
    const float* gammas     = (const float*)d_in[3];
    float* out = (float*)d_out;

    const int N = in_sizes[1];                    // one target per row
    const int nwaves  = (N + 127) / 128;          // 128 rows per wave
    const int nblocks = (nwaves + 3) / 4;         // 4 waves per block

    float* partial = (float*)d_ws;                // nblocks floats (ws >> this)

    adafocal_partial<<<nblocks, 256, 0, stream>>>(inp, targetp, bin_uppers, gammas, partial, N);
    adafocal_final<<<1, 256, 0, stream>>>(partial, out, nblocks);
}

// Round 9
// 95.439 us; speedup vs baseline: 1.1159x; 1.1159x over previous
//
#include <hip/hip_runtime.h>

#define NBINS 15

typedef float f32x4 __attribute__((ext_vector_type(4)));

__device__ __forceinline__ float rdlane_f(float v, int lane) {
    return __int_as_float(__builtin_amdgcn_readlane(__float_as_int(v), lane));
}
__device__ __forceinline__ float rdfirst_f(float v) {
    return __int_as_float(__builtin_amdgcn_readfirstlane(__float_as_int(v)));
}

// e += value moved by DPP
template <int CTRL, int RMASK>
__device__ __forceinline__ float dpp_add(float e) {
    int moved = __builtin_amdgcn_update_dpp(0, __float_as_int(e), CTRL, RMASK, 0xf, true);
    return e + __int_as_float(moved);
}

// Sum within each 32-lane half entirely on the VALU (no DS-pipe ops):
// leaves sum(lanes 0..31) in lane 31, sum(lanes 32..63) in lane 63.
__device__ __forceinline__ float half32_sum(float e) {
    e = dpp_add<0x111, 0xf>(e);  // row_shr:1
    e = dpp_add<0x112, 0xf>(e);  // row_shr:2
    e = dpp_add<0x114, 0xf>(e);  // row_shr:4
    e = dpp_add<0x118, 0xf>(e);  // row_shr:8   -> lanes 15/31/47/63 hold row-of-16 sums
    e = dpp_add<0x142, 0xa>(e);  // row_bcast:15 into rows 1,3 -> lanes 31,63
    return e;
}

// FINAL (R9 = R7 reverted): two-kernel structure, nontemporal streaming loads.
// Measured ladder: R8 A/B proved nt=1 is +11% (95.5 vs 106.5 us): for a 512MB
// pure stream, nt avoids L2 allocation churn on lines that are never re-read.
// R6 proved fused device-scope atomics thrash per-XCD L2 (2.6x regression).
// One wave owns 128 consecutive rows (C=128 fp32).
__global__ __launch_bounds__(256) void adafocal_partial(
    const float* __restrict__ inp,
    const int* __restrict__ target,
    const float* __restrict__ bin_uppers,
    const float* __restrict__ gammas,
    float* __restrict__ partial,
    int N)
{
    __shared__ float  s_g[NBINS];
    __shared__ float2 s_coll[4][128];
    __shared__ float  s_wsum[4];

    if (threadIdx.x < NBINS) s_g[threadIdx.x] = gammas[threadIdx.x];
    __syncthreads();

    // interior bin boundaries, forced to SGPRs (wave-uniform, saves 14 VGPRs)
    float u[NBINS - 1];
    #pragma unroll
    for (int i = 0; i < NBINS - 1; ++i) u[i] = rdfirst_f(bin_uppers[i]);

    const int lane  = threadIdx.x & 63;
    const int wid   = threadIdx.x >> 6;
    const int gwave = blockIdx.x * 4 + wid;
    const int wrow0 = gwave * 128;            // first row of this wave's batch

    // 128 targets for the batch: lane l holds rows 2l, 2l+1
    int2 tt = make_int2(0, 0);
    if (wrow0 + 2 * lane + 1 < N)      tt = ((const int2*)target)[(wrow0 >> 1) + lane];
    else if (wrow0 + 2 * lane < N)     tt.x = target[wrow0 + 2 * lane];

    if (wrow0 + 128 <= N) {
        // hot path: no bounds checks; unroll 8 -> 8KB outstanding loads/wave
        #pragma unroll 8
        for (int k = 0; k < 64; ++k) {
            const f32x4 v = __builtin_nontemporal_load(
                (const f32x4*)(inp + (size_t)(wrow0 + 2 * k) * 128) + lane);

            float e = __expf(v.x) + __expf(v.y) + __expf(v.z) + __expf(v.w);
            e = half32_sum(e);                 // lane31 = row sum, lane63 = row+1 sum

            const int t0 = __builtin_amdgcn_readlane(tt.x, k);
            const int t1 = __builtin_amdgcn_readlane(tt.y, k);
            // x[target]: column c -> lane c>>2 (+32 for upper row), elem c&3
            const float a0  = (t0 & 1) ? v.y : v.x;
            const float b0  = (t0 & 1) ? v.w : v.z;
            const float xt0 = rdlane_f((t0 & 2) ? b0 : a0, t0 >> 2);
            const float a1  = (t1 & 1) ? v.y : v.x;
            const float b1  = (t1 & 1) ? v.w : v.z;
            const float xt1 = rdlane_f((t1 & 2) ? b1 : a1, 32 + (t1 >> 2));

            float2 val;
            val.x = e;
            val.y = (lane < 32) ? xt0 : xt1;
            if ((lane & 31) == 31)
                s_coll[wid][2 * k + (lane >> 5)] = val;
        }
    } else {
        // tail wave (generic N): sentinel (s=1, xt=0) -> exactly 0 contribution
        s_coll[wid][lane]      = make_float2(1.0f, 0.0f);
        s_coll[wid][64 + lane] = make_float2(1.0f, 0.0f);
        for (int k = 0; k < 64; ++k) {
            const int grow = wrow0 + 2 * k;
            if (grow >= N) break;               // uniform
            const bool full = (grow + 1 < N);   // uniform
            f32x4 v = {0.f, 0.f, 0.f, 0.f};
            if (full || lane < 32)
                v = *((const f32x4*)(inp + (size_t)grow * 128) + lane);
            float e = __expf(v.x) + __expf(v.y) + __expf(v.z) + __expf(v.w);
            e = half32_sum(e);
            const int t0 = __builtin_amdgcn_readlane(tt.x, k);
            const int t1 = __builtin_amdgcn_readlane(tt.y, k);
            const float a0  = (t0 & 1) ? v.y : v.x;
            const float b0  = (t0 & 1) ? v.w : v.z;
            const float xt0 = rdlane_f((t0 & 2) ? b0 : a0, t0 >> 2);
            const float a1  = (t1 & 1) ? v.y : v.x;
            const float b1  = (t1 & 1) ? v.w : v.z;
            const float xt1 = rdlane_f((t1 & 2) ? b1 : a1, 32 + (t1 >> 2));
            float2 val;
            val.x = e;
            val.y = (lane < 32) ? xt0 : xt1;
            if (lane == 31 || (full && lane == 63))
                s_coll[wid][2 * k + (lane >> 5)] = val;
        }
    }

    // Phase 2: each lane computes loss for 2 stashed rows (same-wave LDS order)
    float acc = 0.0f;
    #pragma unroll
    for (int h = 0; h < 2; ++h) {
        const float2 cv   = s_coll[wid][64 * h + lane];
        const float logpt = cv.y - __logf(cv.x);
        const float pt    = __expf(logpt);

        // searchsorted(bin_uppers, pt, side='right') = #{uppers <= pt}
        int b = 0;
        #pragma unroll
        for (int i = 0; i < NBINS - 1; ++i)
            b += (u[i] <= pt) ? 1 : 0;

        const float g     = s_g[b];
        const float gsign = (g > 0.0f) ? 1.0f : (g < 0.0f ? -1.0f : 0.0f);
        const float gmag  = fabsf(g);
        const float base  = 1.0f - gsign * pt + 1e-20f;
        const float powv  = (gmag == 1.0f) ? base : __powf(base, gmag);
        acc -= powv * logpt;
    }

    // wave reduce (once per 128 rows)
    #pragma unroll
    for (int m = 1; m < 64; m <<= 1)
        acc += __shfl_xor(acc, m);
    if (lane == 0) s_wsum[wid] = acc;
    __syncthreads();
    if (threadIdx.x == 0)
        partial[blockIdx.x] = (s_wsum[0] + s_wsum[1]) + (s_wsum[2] + s_wsum[3]);
}

__global__ __launch_bounds__(256) void adafocal_final(
    const float* __restrict__ partial, float* __restrict__ out, int nblocks)
{
    __shared__ float s_wsum[4];
    float acc = 0.0f;
    for (int i = threadIdx.x; i < nblocks; i += 256) acc += partial[i];
    #pragma unroll
    for (int m = 1; m < 64; m <<= 1)
        acc += __shfl_xor(acc, m);
    const int lane = threadIdx.x & 63;
    const int wid  = threadIdx.x >> 6;
    if (lane == 0) s_wsum[wid] = acc;
    __syncthreads();
    if (threadIdx.x == 0)
        out[0] = (s_wsum[0] + s_wsum[1]) + (s_wsum[2] + s_wsum[3]);
}

extern "C" void kernel_launch(void* const* d_in, const int* in_sizes, int n_in,
                              void* d_out, int out_size, void* d_ws, size_t ws_size,
                              hipStream_t stream) {
    const float* inp        = (const float*)d_in[0];
    const int*   targetp    = (const int*)d_in[1];
    const float* bin_uppers = (const float*)d_in[2];
    const float* gammas     = (const float*)d_in[3];
    float* out = (float*)d_out;

    const int N = in_sizes[1];                    // one target per row
    const int nwaves  = (N + 127) / 128;          // 128 rows per wave
    const int nblocks = (nwaves + 3) / 4;         // 4 waves per block

    float* partial = (float*)d_ws;                // nblocks floats (ws >> this)

    adafocal_partial<<<nblocks, 256, 0, stream>>>(inp, targetp, bin_uppers, gammas, partial, N);
    adafocal_final<<<1, 256, 0, stream>>>(partial, out, nblocks);
}